// Round 1
// baseline (712.872 us; speedup 1.0000x reference)
//
#include <hip/hip_runtime.h>
#include <hip/hip_bf16.h>
#include <math.h>

#define BB 8
#define LL 2048
#define DD 1024
#define NN 16
#define NC 32      // chunks
#define LC 64      // chunk length (NC*LC == LL)

// ---------------------------------------------------------------------------
// Kernel 1: delta = softplus(x @ W_delta^T + b_delta)   (M=16384, N=1024, K=1024)
// Classic LDS-tiled fp32 GEMM, 64x64 tile, BK=16, 256 threads, 4x4 per thread.
// ---------------------------------------------------------------------------
__global__ __launch_bounds__(256) void gemm_delta(
    const float* __restrict__ x, const float* __restrict__ Wd,
    const float* __restrict__ bd, float* __restrict__ delta) {
  __shared__ float xs[16][68];  // [k][m], pad 4 keeps float4 alignment (68*4=272=16*17)
  __shared__ float ws[16][68];  // [k][n]
  const int m0 = blockIdx.x * 64;
  const int n0 = blockIdx.y * 64;
  const int tid = threadIdx.x;
  const int tx = tid & 15, ty = tid >> 4;  // 16x16 threads
  float acc[4][4] = {};
  for (int kb = 0; kb < 1024; kb += 16) {
    {
      const int r = tid >> 2, k = (tid & 3) << 2;
      float4 xv = *reinterpret_cast<const float4*>(&x[(size_t)(m0 + r) * 1024 + kb + k]);
      xs[k][r] = xv.x; xs[k + 1][r] = xv.y; xs[k + 2][r] = xv.z; xs[k + 3][r] = xv.w;
      float4 wv = *reinterpret_cast<const float4*>(&Wd[(size_t)(n0 + r) * 1024 + kb + k]);
      ws[k][r] = wv.x; ws[k + 1][r] = wv.y; ws[k + 2][r] = wv.z; ws[k + 3][r] = wv.w;
    }
    __syncthreads();
#pragma unroll
    for (int k = 0; k < 16; ++k) {
      float a[4], b[4];
#pragma unroll
      for (int i = 0; i < 4; ++i) a[i] = xs[k][ty * 4 + i];
#pragma unroll
      for (int j = 0; j < 4; ++j) b[j] = ws[k][tx * 4 + j];
#pragma unroll
      for (int i = 0; i < 4; ++i)
#pragma unroll
        for (int j = 0; j < 4; ++j) acc[i][j] = fmaf(a[i], b[j], acc[i][j]);
    }
    __syncthreads();
  }
#pragma unroll
  for (int i = 0; i < 4; ++i) {
    const size_t r = m0 + ty * 4 + i;
#pragma unroll
    for (int j = 0; j < 4; ++j) {
      const int c = n0 + tx * 4 + j;
      float v = acc[i][j] + bd[c];
      float sp = (v > 20.f) ? v : log1pf(__expf(v));  // stable softplus
      delta[r * 1024 + c] = sp;
    }
  }
}

// ---------------------------------------------------------------------------
// Kernel 2: Bin = x @ W_B^T, Cin = x @ W_C^T   (M=16384, N=16+16, K=1024)
// 64 rows/block, 32 cols, BK=64.
// ---------------------------------------------------------------------------
__global__ __launch_bounds__(256) void gemm_bc(
    const float* __restrict__ x, const float* __restrict__ WB,
    const float* __restrict__ WC, float* __restrict__ Bin, float* __restrict__ Cin) {
  __shared__ float xs[64][64];
  __shared__ float ws2[32][65];  // pad -> conflict-free column reads
  const int m0 = blockIdx.x * 64;
  const int tid = threadIdx.x;
  const int tx = tid & 31, ty = tid >> 5;  // col, row-group
  float acc[8] = {};
  for (int kb = 0; kb < 1024; kb += 64) {
#pragma unroll
    for (int s = 0; s < 4; ++s) {
      int flat = (tid + s * 256) * 4;
      int r = flat >> 6, cc = flat & 63;
      float4 v = *reinterpret_cast<const float4*>(&x[(size_t)(m0 + r) * 1024 + kb + cc]);
      *reinterpret_cast<float4*>(&xs[r][cc]) = v;
    }
#pragma unroll
    for (int s = 0; s < 2; ++s) {
      int flat = (tid + s * 256) * 4;
      int j = flat >> 6, cc = flat & 63;
      const float* Wsrc = (j < 16) ? &WB[(size_t)j * 1024 + kb + cc]
                                   : &WC[(size_t)(j - 16) * 1024 + kb + cc];
      float4 v = *reinterpret_cast<const float4*>(Wsrc);
      ws2[j][cc] = v.x; ws2[j][cc + 1] = v.y; ws2[j][cc + 2] = v.z; ws2[j][cc + 3] = v.w;
    }
    __syncthreads();
#pragma unroll
    for (int k = 0; k < 64; ++k) {
      float bv = ws2[tx][k];
#pragma unroll
      for (int i = 0; i < 8; ++i) acc[i] = fmaf(xs[ty + i * 8][k], bv, acc[i]);
    }
    __syncthreads();
  }
#pragma unroll
  for (int i = 0; i < 8; ++i) {
    size_t row = m0 + ty + i * 8;
    if (tx < 16) Bin[row * 16 + tx] = acc[i];
    else         Cin[row * 16 + (tx - 16)] = acc[i];
  }
}

// ---------------------------------------------------------------------------
// Pass 1: per-chunk local scan from h=0. Stores chunk-final h and sum(delta).
// grid (D/256, NC, B)
// ---------------------------------------------------------------------------
__global__ __launch_bounds__(256) void scan_p1(
    const float* __restrict__ delta, const float* __restrict__ x,
    const float* __restrict__ Bin, const float* __restrict__ A_log,
    float* __restrict__ sumd, float* __restrict__ hloc) {
  const int d = blockIdx.x * 256 + threadIdx.x;
  const int c = blockIdx.y, b = blockIdx.z;
  const int t0 = c * LC;
  __shared__ float Bs[LC][NN];
  for (int e = threadIdx.x; e < LC * NN; e += 256)
    Bs[e / NN][e % NN] = Bin[(size_t)(b * LL + t0) * NN + e];
  __syncthreads();
  float A[NN];
#pragma unroll
  for (int n = 0; n < NN; ++n) A[n] = -__expf(A_log[d * NN + n]);
  float h[NN] = {};
  float sd = 0.f;
  const float* dp = delta + (size_t)(b * LL + t0) * DD + d;
  const float* xp = x + (size_t)(b * LL + t0) * DD + d;
  for (int t = 0; t < LC; ++t) {
    float dt = dp[(size_t)t * DD];
    float xt = xp[(size_t)t * DD];
    sd += dt;
    float zb = dt * xt;
#pragma unroll
    for (int n = 0; n < NN; ++n) {
      float ab = __expf(dt * A[n]);
      h[n] = fmaf(ab, h[n], zb * Bs[t][n]);
    }
  }
  sumd[((size_t)b * NC + c) * DD + d] = sd;
#pragma unroll
  for (int n = 0; n < NN; ++n)
    hloc[(((size_t)(b * NC + c)) * NN + n) * DD + d] = h[n];
}

// ---------------------------------------------------------------------------
// Pass 2: cross-chunk combine (32 sequential steps per (b,d,n)); emits h_final.
// ---------------------------------------------------------------------------
__global__ __launch_bounds__(256) void scan_p2(
    const float* __restrict__ A_log, const float* __restrict__ sumd,
    const float* __restrict__ hloc, float* __restrict__ h0,
    float* __restrict__ hfin) {
  const int g = blockIdx.x * 256 + threadIdx.x;  // B*N*D threads
  const int d = g % DD;
  const int n = (g / DD) % NN;
  const int b = g / (DD * NN);
  const float A = -__expf(A_log[d * NN + n]);
  float h = 0.f;
  for (int c = 0; c < NC; ++c) {
    const size_t base = (((size_t)(b * NC + c)) * NN + n) * DD + d;
    h0[base] = h;
    float a = __expf(A * sumd[((size_t)b * NC + c) * DD + d]);
    h = fmaf(a, h, hloc[base]);
  }
  hfin[((size_t)b * DD + d) * NN + n] = h;
}

// ---------------------------------------------------------------------------
// Pass 3: rescan with correct h0, emit y. delta aliases the y region (dy):
// each thread reads delta at (b,t,d) then overwrites it with y.
// grid (D/256, NC, B)
// ---------------------------------------------------------------------------
__global__ __launch_bounds__(256) void scan_p3(
    float* dy,  // delta in, y out (same buffer, same index) -- NOT restrict
    const float* __restrict__ x, const float* __restrict__ Bin,
    const float* __restrict__ Cin, const float* __restrict__ A_log,
    const float* __restrict__ Dp, const float* __restrict__ h0) {
  const int d = blockIdx.x * 256 + threadIdx.x;
  const int c = blockIdx.y, b = blockIdx.z;
  const int t0 = c * LC;
  __shared__ float Bs[LC][NN], Cs[LC][NN];
  for (int e = threadIdx.x; e < LC * NN; e += 256) {
    Bs[e / NN][e % NN] = Bin[(size_t)(b * LL + t0) * NN + e];
    Cs[e / NN][e % NN] = Cin[(size_t)(b * LL + t0) * NN + e];
  }
  __syncthreads();
  float A[NN], h[NN];
#pragma unroll
  for (int n = 0; n < NN; ++n) A[n] = -__expf(A_log[d * NN + n]);
#pragma unroll
  for (int n = 0; n < NN; ++n)
    h[n] = h0[(((size_t)(b * NC + c)) * NN + n) * DD + d];
  const float Dpar = Dp[d];
  float* p = dy + (size_t)(b * LL + t0) * DD + d;
  const float* xp = x + (size_t)(b * LL + t0) * DD + d;
  for (int t = 0; t < LC; ++t) {
    float dt = p[(size_t)t * DD];
    float xt = xp[(size_t)t * DD];
    float zb = dt * xt;
    float acc = Dpar * xt;
#pragma unroll
    for (int n = 0; n < NN; ++n) {
      float ab = __expf(dt * A[n]);
      h[n] = fmaf(ab, h[n], zb * Bs[t][n]);
      acc = fmaf(h[n], Cs[t][n], acc);
    }
    p[(size_t)t * DD] = acc;
  }
}

// ---------------------------------------------------------------------------
extern "C" void kernel_launch(void* const* d_in, const int* in_sizes, int n_in,
                              void* d_out, int out_size, void* d_ws, size_t ws_size,
                              hipStream_t stream) {
  const float* x     = (const float*)d_in[0];
  const float* A_log = (const float*)d_in[1];
  const float* Dp    = (const float*)d_in[2];
  const float* WB    = (const float*)d_in[3];
  const float* WC    = (const float*)d_in[4];
  const float* Wd    = (const float*)d_in[5];
  const float* bd    = (const float*)d_in[6];

  float* y    = (float*)d_out;                 // (B,L,D)
  float* hfin = y + (size_t)BB * LL * DD;      // (B,D,N)
  float* deltaBuf = y;                         // delta lives in y region until pass 3

  float* w    = (float*)d_ws;
  float* Bin  = w;                                   // B*L*N = 262144
  float* Cin  = Bin + (size_t)BB * LL * NN;          // 262144
  float* sumd = Cin + (size_t)BB * LL * NN;          // B*NC*D = 262144
  float* hloc = sumd + (size_t)BB * NC * DD;         // B*NC*N*D = 4194304
  float* h0   = hloc + (size_t)BB * NC * NN * DD;    // 4194304

  gemm_delta<<<dim3(256, 16), 256, 0, stream>>>(x, Wd, bd, deltaBuf);
  gemm_bc<<<dim3(256), 256, 0, stream>>>(x, WB, WC, Bin, Cin);
  scan_p1<<<dim3(DD / 256, NC, BB), 256, 0, stream>>>(deltaBuf, x, Bin, A_log, sumd, hloc);
  scan_p2<<<dim3(BB * NN * DD / 256), 256, 0, stream>>>(A_log, sumd, hloc, h0, hfin);
  scan_p3<<<dim3(DD / 256, NC, BB), 256, 0, stream>>>(deltaBuf, x, Bin, Cin, A_log, Dp, h0);
}

// Round 2
// 298.223 us; speedup vs baseline: 2.3904x; 2.3904x over previous
//
#include <hip/hip_runtime.h>
#include <hip/hip_bf16.h>
#include <math.h>

#define BB 8
#define LL 2048
#define DD 1024
#define NN 16
#define NC 32      // chunks
#define LC 64      // chunk length (NC*LC == LL)

typedef __attribute__((ext_vector_type(8))) short bf16x8;
typedef __attribute__((ext_vector_type(4))) float f32x4;

// ---------------------------------------------------------------------------
// fp32 -> bf16 (RNE) conversion, 8 elements/thread
// ---------------------------------------------------------------------------
__device__ __forceinline__ unsigned short f2bf(float f) {
  unsigned int u = __float_as_uint(f);
  u = (u + 0x7fffu + ((u >> 16) & 1u)) >> 16;
  return (unsigned short)u;
}

__global__ __launch_bounds__(256) void cvt_bf16(const float* __restrict__ in,
                                                unsigned short* __restrict__ out,
                                                int n8) {
  int i = blockIdx.x * 256 + threadIdx.x;
  if (i >= n8) return;
  const float4 a = *reinterpret_cast<const float4*>(in + (size_t)i * 8);
  const float4 b = *reinterpret_cast<const float4*>(in + (size_t)i * 8 + 4);
  ushort4 lo, hi;
  lo.x = f2bf(a.x); lo.y = f2bf(a.y); lo.z = f2bf(a.z); lo.w = f2bf(a.w);
  hi.x = f2bf(b.x); hi.y = f2bf(b.y); hi.z = f2bf(b.z); hi.w = f2bf(b.w);
  *reinterpret_cast<ushort4*>(out + (size_t)i * 8) = lo;
  *reinterpret_cast<ushort4*>(out + (size_t)i * 8 + 4) = hi;
}

// ---------------------------------------------------------------------------
// Kernel 1: delta = softplus(xb @ wb^T + b_delta)  via bf16 MFMA
// M=16384, N=1024, K=1024. 128x128 tile, BK=32, 4 waves (2x2), 4x4 frags/wave.
// m97 structure: global_load_lds width-16 staging, 2-barrier K-loop.
// ---------------------------------------------------------------------------
__device__ __forceinline__ void gload16(const void* g, void* l) {
  __builtin_amdgcn_global_load_lds(
      (const __attribute__((address_space(1))) void*)g,
      (__attribute__((address_space(3))) void*)l, 16, 0, 0);
}

__global__ __launch_bounds__(256) void gemm_delta_mfma(
    const unsigned short* __restrict__ xb, const unsigned short* __restrict__ wb,
    const float* __restrict__ bd, float* __restrict__ delta) {
  __shared__ unsigned short As[128 * 32];  // [row][k] linear
  __shared__ unsigned short Bs[128 * 32];
  const int tid = threadIdx.x;
  const int wave = tid >> 6, lane = tid & 63;
  const int m0 = blockIdx.x * 128, n0 = blockIdx.y * 128;
  const int wr = (wave >> 1) * 64, wc = (wave & 1) * 64;

  // staging geometry: chunk c covers rows c*16..c*16+15; wave handles c=wave, wave+4
  const int c0 = wave, c1 = wave + 4;
  const int srow = lane >> 2;            // 0..15 within chunk
  const int skol = (lane & 3) * 8;       // k element offset (8 bf16 = 16B)

  f32x4 acc[4][4];
#pragma unroll
  for (int i = 0; i < 4; ++i)
#pragma unroll
    for (int j = 0; j < 4; ++j) acc[i][j] = (f32x4){0.f, 0.f, 0.f, 0.f};

  const int l15 = lane & 15, koff = (lane >> 4) * 8;

  for (int kb = 0; kb < 1024; kb += 32) {
    // ---- stage A (x rows) and B (Wd rows) tiles into LDS ----
    gload16(&xb[(size_t)(m0 + c0 * 16 + srow) * 1024 + kb + skol], &As[c0 * 512]);
    gload16(&xb[(size_t)(m0 + c1 * 16 + srow) * 1024 + kb + skol], &As[c1 * 512]);
    gload16(&wb[(size_t)(n0 + c0 * 16 + srow) * 1024 + kb + skol], &Bs[c0 * 512]);
    gload16(&wb[(size_t)(n0 + c1 * 16 + srow) * 1024 + kb + skol], &Bs[c1 * 512]);
    __syncthreads();   // compiler emits vmcnt(0) drain before barrier

    bf16x8 af[4], bfr[4];
#pragma unroll
    for (int mf = 0; mf < 4; ++mf)
      af[mf] = *reinterpret_cast<const bf16x8*>(&As[(wr + mf * 16 + l15) * 32 + koff]);
#pragma unroll
    for (int nf = 0; nf < 4; ++nf)
      bfr[nf] = *reinterpret_cast<const bf16x8*>(&Bs[(wc + nf * 16 + l15) * 32 + koff]);
#pragma unroll
    for (int mf = 0; mf < 4; ++mf)
#pragma unroll
      for (int nf = 0; nf < 4; ++nf)
        acc[mf][nf] = __builtin_amdgcn_mfma_f32_16x16x32_bf16(
            af[mf], bfr[nf], acc[mf][nf], 0, 0, 0);
    __syncthreads();
  }

  // epilogue: C/D layout col=lane&15, row=(lane>>4)*4+reg
  const int crow = (lane >> 4) * 4, ccol = lane & 15;
#pragma unroll
  for (int mf = 0; mf < 4; ++mf) {
#pragma unroll
    for (int nf = 0; nf < 4; ++nf) {
      const int cn = n0 + wc + nf * 16 + ccol;
      const float bias = bd[cn];
#pragma unroll
      for (int r = 0; r < 4; ++r) {
        const size_t rm = (size_t)(m0 + wr + mf * 16 + crow + r);
        float v = acc[mf][nf][r] + bias;
        float sp = (v > 20.f) ? v : log1pf(__expf(v));
        delta[rm * 1024 + cn] = sp;
      }
    }
  }
}

// ---------------------------------------------------------------------------
// Kernel 2: Bin = x @ W_B^T, Cin = x @ W_C^T   (fp32, N=16+16, K=1024)
// ---------------------------------------------------------------------------
__global__ __launch_bounds__(256) void gemm_bc(
    const float* __restrict__ x, const float* __restrict__ WB,
    const float* __restrict__ WC, float* __restrict__ Bin, float* __restrict__ Cin) {
  __shared__ float xs[64][64];
  __shared__ float ws2[32][65];
  const int m0 = blockIdx.x * 64;
  const int tid = threadIdx.x;
  const int tx = tid & 31, ty = tid >> 5;
  float acc[8] = {};
  for (int kb = 0; kb < 1024; kb += 64) {
#pragma unroll
    for (int s = 0; s < 4; ++s) {
      int flat = (tid + s * 256) * 4;
      int r = flat >> 6, cc = flat & 63;
      float4 v = *reinterpret_cast<const float4*>(&x[(size_t)(m0 + r) * 1024 + kb + cc]);
      *reinterpret_cast<float4*>(&xs[r][cc]) = v;
    }
#pragma unroll
    for (int s = 0; s < 2; ++s) {
      int flat = (tid + s * 256) * 4;
      int j = flat >> 6, cc = flat & 63;
      const float* Wsrc = (j < 16) ? &WB[(size_t)j * 1024 + kb + cc]
                                   : &WC[(size_t)(j - 16) * 1024 + kb + cc];
      float4 v = *reinterpret_cast<const float4*>(Wsrc);
      ws2[j][cc] = v.x; ws2[j][cc + 1] = v.y; ws2[j][cc + 2] = v.z; ws2[j][cc + 3] = v.w;
    }
    __syncthreads();
#pragma unroll
    for (int k = 0; k < 64; ++k) {
      float bv = ws2[tx][k];
#pragma unroll
      for (int i = 0; i < 8; ++i) acc[i] = fmaf(xs[ty + i * 8][k], bv, acc[i]);
    }
    __syncthreads();
  }
#pragma unroll
  for (int i = 0; i < 8; ++i) {
    size_t row = m0 + ty + i * 8;
    if (tx < 16) Bin[row * 16 + tx] = acc[i];
    else         Cin[row * 16 + (tx - 16)] = acc[i];
  }
}

// ---------------------------------------------------------------------------
// Pass 1: per-chunk local scan from h=0. Stores chunk-final h and sum(delta).
// ---------------------------------------------------------------------------
__global__ __launch_bounds__(256) void scan_p1(
    const float* __restrict__ delta, const float* __restrict__ x,
    const float* __restrict__ Bin, const float* __restrict__ A_log,
    float* __restrict__ sumd, float* __restrict__ hloc) {
  const int d = blockIdx.x * 256 + threadIdx.x;
  const int c = blockIdx.y, b = blockIdx.z;
  const int t0 = c * LC;
  __shared__ float Bs[LC][NN];
  for (int e = threadIdx.x; e < LC * NN; e += 256)
    Bs[e / NN][e % NN] = Bin[(size_t)(b * LL + t0) * NN + e];
  __syncthreads();
  float A[NN];
#pragma unroll
  for (int n = 0; n < NN; ++n) A[n] = -__expf(A_log[d * NN + n]);
  float h[NN] = {};
  float sd = 0.f;
  const float* dp = delta + (size_t)(b * LL + t0) * DD + d;
  const float* xp = x + (size_t)(b * LL + t0) * DD + d;
  for (int t = 0; t < LC; ++t) {
    float dt = dp[(size_t)t * DD];
    float xt = xp[(size_t)t * DD];
    sd += dt;
    float zb = dt * xt;
#pragma unroll
    for (int n = 0; n < NN; ++n) {
      float ab = __expf(dt * A[n]);
      h[n] = fmaf(ab, h[n], zb * Bs[t][n]);
    }
  }
  sumd[((size_t)b * NC + c) * DD + d] = sd;
#pragma unroll
  for (int n = 0; n < NN; ++n)
    hloc[(((size_t)(b * NC + c)) * NN + n) * DD + d] = h[n];
}

// ---------------------------------------------------------------------------
// Pass 2: cross-chunk combine; emits h_final.
// ---------------------------------------------------------------------------
__global__ __launch_bounds__(256) void scan_p2(
    const float* __restrict__ A_log, const float* __restrict__ sumd,
    const float* __restrict__ hloc, float* __restrict__ h0,
    float* __restrict__ hfin) {
  const int g = blockIdx.x * 256 + threadIdx.x;
  const int d = g % DD;
  const int n = (g / DD) % NN;
  const int b = g / (DD * NN);
  const float A = -__expf(A_log[d * NN + n]);
  float h = 0.f;
  for (int c = 0; c < NC; ++c) {
    const size_t base = (((size_t)(b * NC + c)) * NN + n) * DD + d;
    h0[base] = h;
    float a = __expf(A * sumd[((size_t)b * NC + c) * DD + d]);
    h = fmaf(a, h, hloc[base]);
  }
  hfin[((size_t)b * DD + d) * NN + n] = h;
}

// ---------------------------------------------------------------------------
// Pass 3: rescan with correct h0, emit y (delta aliases y region).
// ---------------------------------------------------------------------------
__global__ __launch_bounds__(256) void scan_p3(
    float* dy, const float* __restrict__ x, const float* __restrict__ Bin,
    const float* __restrict__ Cin, const float* __restrict__ A_log,
    const float* __restrict__ Dp, const float* __restrict__ h0) {
  const int d = blockIdx.x * 256 + threadIdx.x;
  const int c = blockIdx.y, b = blockIdx.z;
  const int t0 = c * LC;
  __shared__ float Bs[LC][NN], Cs[LC][NN];
  for (int e = threadIdx.x; e < LC * NN; e += 256) {
    Bs[e / NN][e % NN] = Bin[(size_t)(b * LL + t0) * NN + e];
    Cs[e / NN][e % NN] = Cin[(size_t)(b * LL + t0) * NN + e];
  }
  __syncthreads();
  float A[NN], h[NN];
#pragma unroll
  for (int n = 0; n < NN; ++n) A[n] = -__expf(A_log[d * NN + n]);
#pragma unroll
  for (int n = 0; n < NN; ++n)
    h[n] = h0[(((size_t)(b * NC + c)) * NN + n) * DD + d];
  const float Dpar = Dp[d];
  float* p = dy + (size_t)(b * LL + t0) * DD + d;
  const float* xp = x + (size_t)(b * LL + t0) * DD + d;
  for (int t = 0; t < LC; ++t) {
    float dt = p[(size_t)t * DD];
    float xt = xp[(size_t)t * DD];
    float zb = dt * xt;
    float acc = Dpar * xt;
#pragma unroll
    for (int n = 0; n < NN; ++n) {
      float ab = __expf(dt * A[n]);
      h[n] = fmaf(ab, h[n], zb * Bs[t][n]);
      acc = fmaf(h[n], Cs[t][n], acc);
    }
    p[(size_t)t * DD] = acc;
  }
}

// ---------------------------------------------------------------------------
extern "C" void kernel_launch(void* const* d_in, const int* in_sizes, int n_in,
                              void* d_out, int out_size, void* d_ws, size_t ws_size,
                              hipStream_t stream) {
  const float* x     = (const float*)d_in[0];
  const float* A_log = (const float*)d_in[1];
  const float* Dp    = (const float*)d_in[2];
  const float* WB    = (const float*)d_in[3];
  const float* WC    = (const float*)d_in[4];
  const float* Wd    = (const float*)d_in[5];
  const float* bd    = (const float*)d_in[6];

  float* y    = (float*)d_out;                 // (B,L,D)
  float* hfin = y + (size_t)BB * LL * DD;      // (B,D,N)
  float* deltaBuf = y;                         // delta aliases y until pass 3

  float* w    = (float*)d_ws;
  float* Bin  = w;                                   // 1 MB
  float* Cin  = Bin + (size_t)BB * LL * NN;          // 1 MB
  float* sumd = Cin + (size_t)BB * LL * NN;          // 1 MB
  float* hloc = sumd + (size_t)BB * NC * DD;         // 16 MB
  float* h0   = hloc + (size_t)BB * NC * NN * DD;    // 16 MB
  unsigned short* xbf = (unsigned short*)(h0 + (size_t)BB * NC * NN * DD);  // 32 MB
  unsigned short* wdbf = xbf + (size_t)BB * LL * DD;                        // 2 MB

  // bf16 conversions
  cvt_bf16<<<dim3((BB * LL * DD / 8 + 255) / 256), 256, 0, stream>>>(x, xbf, BB * LL * DD / 8);
  cvt_bf16<<<dim3((DD * DD / 8 + 255) / 256), 256, 0, stream>>>(Wd, wdbf, DD * DD / 8);

  gemm_delta_mfma<<<dim3(BB * LL / 128, DD / 128), 256, 0, stream>>>(xbf, wdbf, bd, deltaBuf);
  gemm_bc<<<dim3(256), 256, 0, stream>>>(x, WB, WC, Bin, Cin);
  scan_p1<<<dim3(DD / 256, NC, BB), 256, 0, stream>>>(deltaBuf, x, Bin, A_log, sumd, hloc);
  scan_p2<<<dim3(BB * NN * DD / 256), 256, 0, stream>>>(A_log, sumd, hloc, h0, hfin);
  scan_p3<<<dim3(DD / 256, NC, BB), 256, 0, stream>>>(deltaBuf, x, Bin, Cin, A_log, Dp, h0);
}